// Round 3
// baseline (208.079 us; speedup 1.0000x reference)
//
#include <hip/hip_runtime.h>
#include <hip/hip_bf16.h>

#define RANK 16
#define BATCH 32768
#define K_DIM 4096   // A1*B1
#define N_DIM 64     // A2*B2
#define LSTR 68      // LDS row stride (floats)

typedef __bf16 bf16x8 __attribute__((ext_vector_type(8)));
typedef float floatx4 __attribute__((ext_vector_type(4)));
typedef unsigned short ushort8 __attribute__((ext_vector_type(8)));

__device__ inline unsigned short f2bf(float f) {
  unsigned u = __builtin_bit_cast(unsigned, f);
  u += 0x7fffu + ((u >> 16) & 1u);   // round-to-nearest-even
  return (unsigned short)(u >> 16);
}

__device__ inline bf16x8 cvt8(float4 a0, float4 a1) {
  ushort8 au;
  au[0] = f2bf(a0.x); au[1] = f2bf(a0.y); au[2] = f2bf(a0.z); au[3] = f2bf(a0.w);
  au[4] = f2bf(a1.x); au[5] = f2bf(a1.y); au[6] = f2bf(a1.z); au[7] = f2bf(a1.w);
  return __builtin_bit_cast(bf16x8, au);
}

// wT[n][k] = w[k][n] = sum_r s[i][j]*a[r][i][j]*b[r][kk][l]
__global__ __launch_bounds__(256) void build_wT(
    const float* __restrict__ s, const float* __restrict__ a,
    const float* __restrict__ b, unsigned short* __restrict__ wT) {
  int idx = blockIdx.x * 256 + threadIdx.x;   // idx = n*4096 + k
  int n = idx >> 12;
  int k = idx & 4095;
  int j = n >> 3, l = n & 7;
  int i = k >> 6, kk = k & 63;
  float acc = 0.f;
  #pragma unroll
  for (int r = 0; r < RANK; ++r) {
    acc += a[r * 512 + i * 8 + j] * b[r * 512 + kk * 8 + l];
  }
  acc *= s[i * 8 + j];
  wT[idx] = f2bf(acc);
}

// Block = 256 thr = 4 waves = 2 row-tiles x 2 K-halves. Each wave:
// 16 rows x 64 cols x K=2048 via mfma_f32_16x16x32_bf16, 2-stage reg
// pipeline. Per-block cyclic K-phase rotation spreads the chip-wide
// instantaneous address stream across the full 8KB half-row span so HBM
// channel interleave stays balanced (x rows are 16KB-strided; lockstep
// K-walk would alias all concurrent reads to few channels).
__global__ __launch_bounds__(256, 4) void kron_gemm(
    const float* __restrict__ x, const unsigned short* __restrict__ wT,
    const float* __restrict__ bias, float* __restrict__ out) {
  __shared__ __align__(16) float red[2][32][LSTR];

  const int tid  = threadIdx.x;
  const int lane = tid & 63;
  const int wave = tid >> 6;
  const int rt   = wave & 1;     // row tile within block
  const int kh   = wave >> 1;    // K half
  const int ln15 = lane & 15;    // A row / B col / D col
  const int kseg = lane >> 4;    // 0..3

  const int m0 = blockIdx.x * 32 + rt * 16;
  const float* xp = x + (size_t)(m0 + ln15) * K_DIM + kh * 2048 + kseg * 8;
  const unsigned short* wp = wT + (size_t)ln15 * K_DIM + kh * 2048 + kseg * 8;

  const int phase = (int)((blockIdx.x * 17u) & 63u);
  // logical iter i -> physical float offset within the K-half
#define XOFF(i) ((((i) + phase) & 63) * 32)

  floatx4 acc[4] = {};

  // ---- prologue: preload pipeline stages A (it=0) and B (it=1) ----
  int o0 = XOFF(0), o1 = XOFF(1);
  float4 xa0 = *(const float4*)(xp + o0), xb0 = *(const float4*)(xp + o0 + 4);
  float4 xa1 = *(const float4*)(xp + o1), xb1 = *(const float4*)(xp + o1 + 4);
  bf16x8 w0[4], w1[4];
  #pragma unroll
  for (int c = 0; c < 4; ++c) {
    w0[c] = *(const bf16x8*)(wp + (size_t)c * 16 * K_DIM + o0);
    w1[c] = *(const bf16x8*)(wp + (size_t)c * 16 * K_DIM + o1);
  }

  // ---- steady state: 64 K-iterations total, compute 0..61 here ----
  for (int it = 0; it < 62; it += 2) {
    // stage A: compute logical it, prefetch it+2
    {
      bf16x8 af = cvt8(xa0, xb0);
      const int on = XOFF(it + 2);
      xa0 = *(const float4*)(xp + on);
      xb0 = *(const float4*)(xp + on + 4);
      #pragma unroll
      for (int c = 0; c < 4; ++c) {
        acc[c] = __builtin_amdgcn_mfma_f32_16x16x32_bf16(af, w0[c], acc[c], 0, 0, 0);
        w0[c] = *(const bf16x8*)(wp + (size_t)c * 16 * K_DIM + on);
      }
    }
    // stage B: compute logical it+1, prefetch it+3
    {
      bf16x8 bf = cvt8(xa1, xb1);
      const int on = XOFF(it + 3);
      xa1 = *(const float4*)(xp + on);
      xb1 = *(const float4*)(xp + on + 4);
      #pragma unroll
      for (int c = 0; c < 4; ++c) {
        acc[c] = __builtin_amdgcn_mfma_f32_16x16x32_bf16(bf, w1[c], acc[c], 0, 0, 0);
        w1[c] = *(const bf16x8*)(wp + (size_t)c * 16 * K_DIM + on);
      }
    }
  }
  // ---- epilogue: compute logical 62, 63 ----
  {
    bf16x8 af = cvt8(xa0, xb0);
    #pragma unroll
    for (int c = 0; c < 4; ++c)
      acc[c] = __builtin_amdgcn_mfma_f32_16x16x32_bf16(af, w0[c], acc[c], 0, 0, 0);
    bf16x8 bf = cvt8(xa1, xb1);
    #pragma unroll
    for (int c = 0; c < 4; ++c)
      acc[c] = __builtin_amdgcn_mfma_f32_16x16x32_bf16(bf, w1[c], acc[c], 0, 0, 0);
  }
#undef XOFF

  // ---- cross-K-half reduce via LDS ----
  #pragma unroll
  for (int c = 0; c < 4; ++c) {
    #pragma unroll
    for (int r = 0; r < 4; ++r) {
      red[kh][rt * 16 + kseg * 4 + r][c * 16 + ln15] = acc[c][r];
    }
  }
  __syncthreads();

  // ---- coalesced epilogue: 32 rows x 64 cols, float4 per thread x2 ----
  const size_t obase = (size_t)blockIdx.x * 32 * N_DIM;
  #pragma unroll
  for (int p = 0; p < 2; ++p) {
    int f   = tid + p * 256;     // 0..511
    int row = f >> 4;            // 0..31
    int c4  = f & 15;            // 0..15
    float4 v0 = *(const float4*)&red[0][row][c4 * 4];
    float4 v1 = *(const float4*)&red[1][row][c4 * 4];
    float4 bv = *(const float4*)&bias[c4 * 4];
    float4 o;
    o.x = v0.x + v1.x + bv.x;
    o.y = v0.y + v1.y + bv.y;
    o.z = v0.z + v1.z + bv.z;
    o.w = v0.w + v1.w + bv.w;
    *(float4*)(out + obase + (size_t)row * N_DIM + c4 * 4) = o;
  }
}

extern "C" void kernel_launch(void* const* d_in, const int* in_sizes, int n_in,
                              void* d_out, int out_size, void* d_ws, size_t ws_size,
                              hipStream_t stream) {
  const float* x    = (const float*)d_in[0];
  const float* s    = (const float*)d_in[1];
  const float* a    = (const float*)d_in[2];
  const float* b    = (const float*)d_in[3];
  const float* bias = (const float*)d_in[4];
  float* out = (float*)d_out;
  unsigned short* wT = (unsigned short*)d_ws;   // 4096*64*2B = 512 KB

  build_wT<<<(N_DIM * K_DIM) / 256, 256, 0, stream>>>(s, a, b, wT);
  kron_gemm<<<BATCH / 32, 256, 0, stream>>>(x, wT, bias, out);
}

// Round 4
// 138.303 us; speedup vs baseline: 1.5045x; 1.5045x over previous
//
#include <hip/hip_runtime.h>
#include <hip/hip_bf16.h>

#define RANK 16
#define BATCH 32768
#define K_DIM 4096   // A1*B1
#define N_DIM 64     // A2*B2
#define CHUNK 128    // K floats staged per buffer (512B per row)
#define NCHUNK 32    // 4096/128
#define ROWB 64      // rows per block

typedef __bf16 bf16x8 __attribute__((ext_vector_type(8)));
typedef float floatx4 __attribute__((ext_vector_type(4)));
typedef unsigned short ushort8 __attribute__((ext_vector_type(8)));

__device__ inline unsigned short f2bf(float f) {
  unsigned u = __builtin_bit_cast(unsigned, f);
  u += 0x7fffu + ((u >> 16) & 1u);   // round-to-nearest-even
  return (unsigned short)(u >> 16);
}

__device__ inline bf16x8 cvt8(float4 a0, float4 a1) {
  ushort8 au;
  au[0] = f2bf(a0.x); au[1] = f2bf(a0.y); au[2] = f2bf(a0.z); au[3] = f2bf(a0.w);
  au[4] = f2bf(a1.x); au[5] = f2bf(a1.y); au[6] = f2bf(a1.z); au[7] = f2bf(a1.w);
  return __builtin_bit_cast(bf16x8, au);
}

// wT[n][k] = w[k][n] = sum_r s[i][j]*a[r][i][j]*b[r][kk][l]
__global__ __launch_bounds__(256) void build_wT(
    const float* __restrict__ s, const float* __restrict__ a,
    const float* __restrict__ b, unsigned short* __restrict__ wT) {
  int idx = blockIdx.x * 256 + threadIdx.x;   // idx = n*4096 + k
  int n = idx >> 12;
  int k = idx & 4095;
  int j = n >> 3, l = n & 7;
  int i = k >> 6, kk = k & 63;
  float acc = 0.f;
  #pragma unroll
  for (int r = 0; r < RANK; ++r) {
    acc += a[r * 512 + i * 8 + j] * b[r * 512 + kk * 8 + l];
  }
  acc *= s[i * 8 + j];
  wT[idx] = f2bf(acc);
}

// Block = 64 rows x 64 cols, 4 waves (each wave: all 64 rows x 16 cols).
// x staged to LDS via global_load_lds_dwordx4: each instruction = 1024
// CONTIGUOUS bytes (2 rows x 512B chunk) = 8 full cache lines, vs 16
// half-used lines for the old fragment-layout loads. XOR swizzle
// (unit ^= row&7, within-line) applied on the GLOBAL source (linear LDS
// dest, rule: both-sides-or-neither) and on the ds_read side -> even
// bank spread. One w-load per K-step reused across 4 A-frags.
__global__ __launch_bounds__(256, 2) void kron_gemm(
    const float* __restrict__ x, const unsigned short* __restrict__ wT,
    const float* __restrict__ bias, float* __restrict__ out) {
  __shared__ __align__(16) float As[2][ROWB * CHUNK];   // 2 x 32 KB

  const int tid   = threadIdx.x;
  const int lane  = tid & 63;
  const int wave  = tid >> 6;
  const int ln15  = lane & 15;    // A row within frag / w col / D col
  const int kseg  = lane >> 4;    // 0..3
  const int u     = lane & 31;    // 16B unit within a row-chunk (staging)
  const int rhalf = lane >> 5;    // staging: which row of the pair
  const int m0    = blockIdx.x * ROWB;
  const int sw    = (ln15 & 7) << 4;   // read-side swizzle byte XOR

  // this wave's 16 output cols
  const unsigned short* wp = wT + (size_t)(wave * 16 + ln15) * K_DIM + kseg * 8;

  floatx4 acc[4] = {};

  // stage chunk c into buffer buf: 8 instrs/wave, rows wave*16 .. +15
  auto stage = [&](int buf, int c) {
    #pragma unroll
    for (int j = 0; j < 8; ++j) {
      const int row = wave * 16 + 2 * j + rhalf;       // per-lane (bit5)
      const int sb  = (u * 16) ^ ((row & 7) << 4);     // swizzled src byte
      const float* src = x + (size_t)(m0 + row) * K_DIM + c * CHUNK + (sb >> 2);
      float* dst = &As[buf][(wave * 16 + 2 * j) * CHUNK];  // wave-uniform base
      __builtin_amdgcn_global_load_lds(
          (const __attribute__((address_space(1))) void*)(const void*)src,
          (__attribute__((address_space(3))) void*)(void*)dst,
          16, 0, 0);
    }
  };

  stage(0, 0);
  __syncthreads();

  for (int c = 0; c < NCHUNK; ++c) {
    const int cur = c & 1;
    if (c + 1 < NCHUNK) stage(cur ^ 1, c + 1);   // issue-early, in flight under compute

    const char* Ab = (const char*)&As[cur][0];
    #pragma unroll
    for (int t = 0; t < 4; ++t) {                 // K-steps of 32 within chunk
      bf16x8 wf = *(const bf16x8*)(wp + c * CHUNK + t * 32);
      #pragma unroll
      for (int f = 0; f < 4; ++f) {               // 4 row-frags = 64 rows
        const int row = 16 * f + ln15;
        const int b0  = t * 128 + kseg * 32;
        float4 lo = *(const float4*)(Ab + row * 512 + ((b0)      ^ sw));
        float4 hi = *(const float4*)(Ab + row * 512 + ((b0 + 16) ^ sw));
        acc[f] = __builtin_amdgcn_mfma_f32_16x16x32_bf16(cvt8(lo, hi), wf, acc[f], 0, 0, 0);
      }
    }
    __syncthreads();   // drains my gll writes (vmcnt0) + all waves done reading cur
  }

  // epilogue: D col = lane&15, row = kseg*4 + r  (m89-verified mapping)
  const int col = wave * 16 + ln15;
  const float bv = bias[col];
  #pragma unroll
  for (int f = 0; f < 4; ++f) {
    float* op = out + (size_t)(m0 + 16 * f + kseg * 4) * N_DIM + col;
    #pragma unroll
    for (int r = 0; r < 4; ++r)
      op[(size_t)r * N_DIM] = acc[f][r] + bv;
  }
}

extern "C" void kernel_launch(void* const* d_in, const int* in_sizes, int n_in,
                              void* d_out, int out_size, void* d_ws, size_t ws_size,
                              hipStream_t stream) {
  const float* x    = (const float*)d_in[0];
  const float* s    = (const float*)d_in[1];
  const float* a    = (const float*)d_in[2];
  const float* b    = (const float*)d_in[3];
  const float* bias = (const float*)d_in[4];
  float* out = (float*)d_out;
  unsigned short* wT = (unsigned short*)d_ws;   // 4096*64*2B = 512 KB

  build_wT<<<(N_DIM * K_DIM) / 256, 256, 0, stream>>>(s, a, b, wT);
  kron_gemm<<<BATCH / ROWB, 256, 0, stream>>>(x, wT, bias, out);
}